// Round 5
// baseline (32.358 us; speedup 1.0000x reference)
//
#include <hip/hip_runtime.h>
#include <math.h>

#define RPOOL 5

// ---- cross-lane reductions without the DS pipe ------------------------------
// XOR-butterfly over masks {1,2,7,15,16,32}: 6 linearly independent XOR masks
// spanning all 64 lanes, so after the 6 combining steps EVERY lane holds the
// full-wave reduce. Masks 1,2,7,15 are intra-row DPP (quad_perm / mirrors);
// 16 and 32 use gfx950 permlane swaps (VALU, not LDS).
// NOTE: dpp_ctrl must be a compile-time constant -> template parameter.

template <int CTRL>
__device__ __forceinline__ float dpp_fmax(float v) {
    const int iv = __float_as_int(v);
    const int o  = __builtin_amdgcn_update_dpp(iv, iv, CTRL, 0xf, 0xf, false);
    return fmaxf(v, __int_as_float(o));
}
template <int CTRL>
__device__ __forceinline__ float dpp_fmin(float v) {
    const int iv = __float_as_int(v);
    const int o  = __builtin_amdgcn_update_dpp(iv, iv, CTRL, 0xf, 0xf, false);
    return fminf(v, __int_as_float(o));
}

// fmax/fmin(r.x, r.y) with both swap inputs = v gives op(v[i], v[i^K]) on
// every lane, independent of which half the HW assigns to which output.
__device__ __forceinline__ float swap16_fmax(float v) {
#if __has_builtin(__builtin_amdgcn_permlane16_swap)
    const unsigned u = __float_as_uint(v);
    auto r = __builtin_amdgcn_permlane16_swap(u, u, false, false);
    return fmaxf(__uint_as_float((unsigned)r[0]), __uint_as_float((unsigned)r[1]));
#else
    return fmaxf(v, __shfl_xor(v, 16, 64));
#endif
}
__device__ __forceinline__ float swap16_fmin(float v) {
#if __has_builtin(__builtin_amdgcn_permlane16_swap)
    const unsigned u = __float_as_uint(v);
    auto r = __builtin_amdgcn_permlane16_swap(u, u, false, false);
    return fminf(__uint_as_float((unsigned)r[0]), __uint_as_float((unsigned)r[1]));
#else
    return fminf(v, __shfl_xor(v, 16, 64));
#endif
}
__device__ __forceinline__ float swap32_fmax(float v) {
#if __has_builtin(__builtin_amdgcn_permlane32_swap)
    const unsigned u = __float_as_uint(v);
    auto r = __builtin_amdgcn_permlane32_swap(u, u, false, false);
    return fmaxf(__uint_as_float((unsigned)r[0]), __uint_as_float((unsigned)r[1]));
#else
    return fmaxf(v, __shfl_xor(v, 32, 64));
#endif
}
__device__ __forceinline__ float swap32_fmin(float v) {
#if __has_builtin(__builtin_amdgcn_permlane32_swap)
    const unsigned u = __float_as_uint(v);
    auto r = __builtin_amdgcn_permlane32_swap(u, u, false, false);
    return fminf(__uint_as_float((unsigned)r[0]), __uint_as_float((unsigned)r[1]));
#else
    return fminf(v, __shfl_xor(v, 32, 64));
#endif
}

__device__ __forceinline__ float wave_fmax(float v) {
    v = dpp_fmax<0xB1>(v);   // quad_perm [1,0,3,2]  : xor 1
    v = dpp_fmax<0x4E>(v);   // quad_perm [2,3,0,1]  : xor 2
    v = dpp_fmax<0x141>(v);  // row_half_mirror      : xor 7
    v = dpp_fmax<0x140>(v);  // row_mirror           : xor 15
    v = swap16_fmax(v);      //                        xor 16
    v = swap32_fmax(v);      //                        xor 32
    return v;
}
__device__ __forceinline__ float wave_fmin(float v) {
    v = dpp_fmin<0xB1>(v);
    v = dpp_fmin<0x4E>(v);
    v = dpp_fmin<0x141>(v);
    v = dpp_fmin<0x140>(v);
    v = swap16_fmin(v);
    v = swap32_fmin(v);
    return v;
}

__global__ __launch_bounds__(256, 8)
void minmax_pool_sort_kernel(const float* __restrict__ x,
                             const int* __restrict__ lengths,
                             float* __restrict__ out,
                             int n, int L) {
    const int lane = threadIdx.x & 63;
    const int row  = blockIdx.x * 4 + (threadIdx.x >> 6);
    if (row >= n) return;

    // l is wave-uniform: force to SGPR so boundary math runs on the SALU.
    const int l = __builtin_amdgcn_readfirstlane(lengths[row]);
    const float* xr = x + (long long)row * L;

    int s[RPOOL], e[RPOOL];
#pragma unroll
    for (int j = 0; j < RPOOL; ++j) {
        s[j] = (j * l) / RPOOL;                      // floor(j*l/R)
        e[j] = ((j + 1) * l + RPOOL - 1) / RPOOL;    // ceil((j+1)*l/R)
    }

    // Max window = ceil(1000/5)+1 = 201 elems <= 51 float4s <= 64 lanes:
    // one aligned float4 load per window. All 5 issued upfront.
    float4 v[RPOOL];
    int    t0[RPOOL];
#pragma unroll
    for (int j = 0; j < RPOOL; ++j) {
        const int sa = s[j] & ~3;            // 16B-aligned start
        const int t  = sa + lane * 4;
        t0[j] = t;
        const int idx = (t < e[j]) ? t : 0;  // clamp OOB lanes into the row
        v[j] = *reinterpret_cast<const float4*>(xr + idx);
    }

    float vals[2 * RPOOL];
#pragma unroll
    for (int j = 0; j < RPOOL; ++j) {
        const float vv0 = v[j].x, vv1 = v[j].y, vv2 = v[j].z, vv3 = v[j].w;
        const int t = t0[j];
        const bool ok0 = (t     >= s[j]) & (t     < e[j]);
        const bool ok1 = (t + 1 >= s[j]) & (t + 1 < e[j]);
        const bool ok2 = (t + 2 >= s[j]) & (t + 2 < e[j]);
        const bool ok3 = (t + 3 >= s[j]) & (t + 3 < e[j]);
        const float m0 = ok0 ? vv0 : -INFINITY, n0 = ok0 ? vv0 : INFINITY;
        const float m1 = ok1 ? vv1 : -INFINITY, n1 = ok1 ? vv1 : INFINITY;
        const float m2 = ok2 ? vv2 : -INFINITY, n2 = ok2 ? vv2 : INFINITY;
        const float m3 = ok3 ? vv3 : -INFINITY, n3 = ok3 ? vv3 : INFINITY;

        float mx = fmaxf(fmaxf(m0, m1), fmaxf(m2, m3));
        float mn = fminf(fminf(n0, n1), fminf(n2, n3));

        vals[j]         = wave_fmax(mx);   // all-lanes DPP/permlane butterfly
        vals[RPOOL + j] = wave_fmin(mn);
    }

    // Sort 10 ascending — fully-unrolled bubble network (known correct).
#pragma unroll
    for (int i = 0; i < 2 * RPOOL - 1; ++i) {
#pragma unroll
        for (int k = 0; k < 2 * RPOOL - 1 - i; ++k) {
            const float a = vals[k];
            const float b = vals[k + 1];
            vals[k]     = fminf(a, b);
            vals[k + 1] = fmaxf(a, b);
        }
    }

    // Coalesced store: lanes 0..9 store one value each.
    float ov = vals[0];
#pragma unroll
    for (int k = 1; k < 2 * RPOOL; ++k) ov = (lane == k) ? vals[k] : ov;
    if (lane < 2 * RPOOL) out[(long long)row * (2 * RPOOL) + lane] = ov;
}

extern "C" void kernel_launch(void* const* d_in, const int* in_sizes, int n_in,
                              void* d_out, int out_size, void* d_ws, size_t ws_size,
                              hipStream_t stream) {
    const float* x       = (const float*)d_in[0];
    const int*   lengths = (const int*)d_in[1];
    float*       out     = (float*)d_out;

    const int n = in_sizes[1];            // N rows
    const int L = in_sizes[0] / n;        // row stride (1000)

    const int blocks = (n + 3) / 4;       // 4 waves (rows) per 256-thread block
    hipLaunchKernelGGL(minmax_pool_sort_kernel, dim3(blocks), dim3(256), 0, stream,
                       x, lengths, out, n, L);
}

// Round 6
// 30.548 us; speedup vs baseline: 1.0592x; 1.0592x over previous
//
#include <hip/hip_runtime.h>
#include <math.h>

#define RPOOL 5

__global__ __launch_bounds__(256, 4)
void minmax_pool_sort_kernel(const float* __restrict__ x,
                             const int* __restrict__ lengths,
                             float* __restrict__ out,
                             int n, int L) {
    const int lane = threadIdx.x & 63;
    // Row index is wave-uniform: compute it as such so lengths[] can be
    // a scalar (SMEM) load issued immediately.
    const int row = __builtin_amdgcn_readfirstlane(blockIdx.x * 4 + (threadIdx.x >> 6));
    if (row >= n) return;

    const int l = __builtin_amdgcn_readfirstlane(lengths[row]);
    const float* xr = x + (long long)row * L;

    int s[RPOOL], e[RPOOL];
#pragma unroll
    for (int j = 0; j < RPOOL; ++j) {
        s[j] = (j * l) / RPOOL;                      // floor(j*l/R)
        e[j] = ((j + 1) * l + RPOOL - 1) / RPOOL;    // ceil((j+1)*l/R)
    }

    // Max window = ceil(1000/5)+1 = 201 elems <= 51 float4s <= 64 lanes:
    // one aligned float4 load per window; all 5 issued upfront.
    float4 v[RPOOL];
    int    t0[RPOOL];
#pragma unroll
    for (int j = 0; j < RPOOL; ++j) {
        const int sa = s[j] & ~3;            // 16B-aligned start
        const int t  = sa + lane * 4;
        t0[j] = t;
        const int idx = (t < e[j]) ? t : 0;  // clamp OOB lanes into the row
        v[j] = *reinterpret_cast<const float4*>(xr + idx);
    }

    // Per-lane masked 4-element tree reduce for every window first...
    float mx[RPOOL], mn[RPOOL];
#pragma unroll
    for (int j = 0; j < RPOOL; ++j) {
        const float vv0 = v[j].x, vv1 = v[j].y, vv2 = v[j].z, vv3 = v[j].w;
        const int t = t0[j];
        const bool ok0 = (t     >= s[j]) & (t     < e[j]);
        const bool ok1 = (t + 1 >= s[j]) & (t + 1 < e[j]);
        const bool ok2 = (t + 2 >= s[j]) & (t + 2 < e[j]);
        const bool ok3 = (t + 3 >= s[j]) & (t + 3 < e[j]);
        const float m0 = ok0 ? vv0 : -INFINITY, n0 = ok0 ? vv0 : INFINITY;
        const float m1 = ok1 ? vv1 : -INFINITY, n1 = ok1 ? vv1 : INFINITY;
        const float m2 = ok2 ? vv2 : -INFINITY, n2 = ok2 ? vv2 : INFINITY;
        const float m3 = ok3 ? vv3 : -INFINITY, n3 = ok3 ? vv3 : INFINITY;
        mx[j] = fmaxf(fmaxf(m0, m1), fmaxf(m2, m3));
        mn[j] = fminf(fminf(n0, n1), fminf(n2, n3));
    }

    // ...then STEP-MAJOR butterfly: each level issues 10 independent
    // cross-lane ops, so DS latency overlaps 10-wide instead of
    // serializing 5 windows' chains back-to-back.
#pragma unroll
    for (int off = 32; off > 0; off >>= 1) {
#pragma unroll
        for (int j = 0; j < RPOOL; ++j) {
            mx[j] = fmaxf(mx[j], __shfl_xor(mx[j], off, 64));
            mn[j] = fminf(mn[j], __shfl_xor(mn[j], off, 64));
        }
    }

    float vals[2 * RPOOL];
#pragma unroll
    for (int j = 0; j < RPOOL; ++j) { vals[j] = mx[j]; vals[RPOOL + j] = mn[j]; }

    // Sort 10 ascending — fully-unrolled bubble network (known correct).
#pragma unroll
    for (int i = 0; i < 2 * RPOOL - 1; ++i) {
#pragma unroll
        for (int k = 0; k < 2 * RPOOL - 1 - i; ++k) {
            const float a = vals[k];
            const float b = vals[k + 1];
            vals[k]     = fminf(a, b);
            vals[k + 1] = fmaxf(a, b);
        }
    }

    // Coalesced store: lanes 0..9 store one value each.
    float ov = vals[0];
#pragma unroll
    for (int k = 1; k < 2 * RPOOL; ++k) ov = (lane == k) ? vals[k] : ov;
    if (lane < 2 * RPOOL) out[(long long)row * (2 * RPOOL) + lane] = ov;
}

extern "C" void kernel_launch(void* const* d_in, const int* in_sizes, int n_in,
                              void* d_out, int out_size, void* d_ws, size_t ws_size,
                              hipStream_t stream) {
    const float* x       = (const float*)d_in[0];
    const int*   lengths = (const int*)d_in[1];
    float*       out     = (float*)d_out;

    const int n = in_sizes[1];            // N rows
    const int L = in_sizes[0] / n;        // row stride (1000)

    const int blocks = (n + 3) / 4;       // 4 waves (rows) per 256-thread block
    hipLaunchKernelGGL(minmax_pool_sort_kernel, dim3(blocks), dim3(256), 0, stream,
                       x, lengths, out, n, L);
}